// Round 12
// baseline (147.411 us; speedup 1.0000x reference)
//
#include <hip/hip_runtime.h>
#include <math.h>

// WaveletLayer: (B=4096, S=50, H=256) fp32.
// Round-11: two-kernel split. r10 proved the fused kernel cannot saturate the
// memory pipe: each block is ~90% compute-phase, ~5 resident -> HBM duty caps
// at ~45% no matter the scheduling. Split:
//   W: stage x -> packed fp16 wavelet pipeline -> y=x+rec (f16 pairs) to d_ws.
//      One barrier, no LN. Compute-bound at ~24us VALU/CU.
//   L: streaming LN: one wave per row-pair, f16x8 loads, packed-f16 (even,odd)
//      reduction chains (12 shuffles/iter), float4 stores. No barriers, no
//      LDS -> streams like fillBuffer (7 TB/s at 10% occupancy).
// Fallback (ws too small): r8 fused kernel verbatim (101us bench).

#define S_LEN 50
#define H_DIM 256
#define NPAIR 25
#define BATCH 4096

typedef _Float16 f16;
typedef __attribute__((ext_vector_type(2))) _Float16 f16x2;
typedef __attribute__((ext_vector_type(4))) _Float16 f16x4;
typedef __attribute__((ext_vector_type(8))) _Float16 f16x8;

// d_ws layout: ft (32 KiB) | y pairs f16x2 [B][25][256] (100 MiB)
#define FT01_OFF 0
#define FT2_OFF (10 * H_DIM)
#define FT3_OFF (18 * H_DIM)
#define FT_BYTES (32 * H_DIM * 4)  // 32768
#define Y_BYTES ((size_t)BATCH * NPAIR * H_DIM * 4)

__device__ constexpr float DLO[6] = {
    0.035226291882100656f, -0.08544127388224149f, -0.13501102001039084f,
    0.4598775021193313f,   0.8068915093133388f,   0.3326705529509569f};
__device__ constexpr float DHI[6] = {
    -0.3326705529509569f,  0.8068915093133388f,  -0.4598775021193313f,
    -0.13501102001039084f, 0.08544127388224149f,  0.035226291882100656f};

static __device__ __forceinline__ f16x2 splat2(f16 v) {
  f16x2 r; r.x = v; r.y = v; return r;
}
static __device__ __forceinline__ f16x2 mk2(float a, float b) {
  f16x2 r; r.x = (f16)a; r.y = (f16)b; return r;
}
static __device__ __forceinline__ f16x2 shfl_pk(f16x2 v, int o) {
  return __builtin_bit_cast(f16x2, __shfl_xor(__builtin_bit_cast(int, v), o));
}

// Transpose+pack the learned filters into [l][h]-major f16x2 in ws.
__global__ void prep_filters(const float* __restrict__ f0,
                             const float* __restrict__ f1,
                             const float* __restrict__ f2,
                             const float* __restrict__ f3,
                             f16x2* __restrict__ ft) {
  const int h = threadIdx.x;
  const int b = blockIdx.x;
  if (b < 10) {
    const int l = b;
    f16x2 v; v.x = (f16)f0[h * 10 + l]; v.y = (f16)f1[h * 10 + l];
    ft[FT01_OFF + l * H_DIM + h] = v;
  } else if (b < 18) {
    const int k = b - 10;
    f16x2 v; v.x = (f16)f2[h * 16 + 2 * k]; v.y = (f16)f2[h * 16 + 2 * k + 1];
    ft[FT2_OFF + k * H_DIM + h] = v;
  } else {
    const int k = b - 18;
    f16x2 v;
    v.x = (f16)f3[h * 27 + 2 * k];
    v.y = (2 * k + 1 < 27) ? (f16)f3[h * 27 + 2 * k + 1] : (f16)0.f;
    ft[FT3_OFF + k * H_DIM + h] = v;
  }
}

// One analysis level, (lo,hi)-packed. out[i] = {cA[i], cD[i]}.
template <int N, class Get>
__device__ __forceinline__ void dwt_f16(const Get& X, f16x2* out) {
  constexpr int M = (N + 5) / 2;
#pragma unroll
  for (int i = 0; i < M; ++i) {
    f16x2 acc = mk2(0.f, 0.f);
#pragma unroll
    for (int j = 0; j < 6; ++j) {
      int idx = 2 * i + j - 4;
      idx = idx < 0 ? -idx : idx;
      idx = idx >= N ? 2 * N - 2 - idx : idx;
      acc += splat2(X(idx)) * mk2(DLO[5 - j], DHI[5 - j]);
    }
    out[i] = acc;
  }
}

// One synthesis level, adjacent-packed output: out2[t] = {rec[2t], rec[2t+1]}.
template <int T, class GLo, class GHi>
__device__ __forceinline__ void idwt_f16(const GLo& lo, const GHi& hi,
                                         f16x2* out2) {
#pragma unroll
  for (int t = 0; t < T / 2; ++t) {
    f16x2 acc = mk2(0.f, 0.f);
#pragma unroll
    for (int k = 0; k < 3; ++k) {
      acc += splat2(lo(t + k)) * mk2(DLO[2 * k + 1], DLO[2 * k]);
      acc += splat2(hi(t + k)) * mk2(DHI[2 * k + 1], DHI[2 * k]);
    }
    out2[t] = acc;
  }
  if constexpr (T & 1) {
    constexpr int t0 = T / 2;
    f16 s = (f16)0.f;
#pragma unroll
    for (int k = 0; k < 3; ++k)
      s += lo(t0 + k) * (f16)DLO[2 * k + 1] + hi(t0 + k) * (f16)DHI[2 * k + 1];
    f16x2 r; r.x = s; r.y = (f16)0.f;
    out2[t0] = r;
  }
}

// Shared core: stage (phase 0) assumed done; xp -> y pairs in yp[25].
template <bool USE_WS>
__device__ __forceinline__ void wavelet_core(
    const f16x2* __restrict__ sp, int h, const f16x2* __restrict__ ft,
    const float* __restrict__ f0, const float* __restrict__ f1,
    const float* __restrict__ f2, const float* __restrict__ f3,
    f16x2* __restrict__ xp, f16x2* __restrict__ yp) {
#pragma unroll
  for (int t = 0; t < NPAIR; ++t) xp[t] = sp[t * H_DIM + h];  // 2-way, free

  f16x2 AD1[27];
  dwt_f16<50>([&](int s) -> f16 { return (s & 1) ? xp[s >> 1].y
                                                 : xp[s >> 1].x; }, AD1);
  f16x2 AD2[16];
  dwt_f16<27>([&](int s) -> f16 { return AD1[s].x; }, AD2);
  f16x2 AD3[10];
  dwt_f16<16>([&](int s) -> f16 { return AD2[s].x; }, AD3);

  if (USE_WS) {
#pragma unroll
    for (int l = 0; l < 10; ++l) AD3[l] *= ft[FT01_OFF + l * H_DIM + h];
#pragma unroll
    for (int k = 0; k < 8; ++k) {
      const f16x2 c = ft[FT2_OFF + k * H_DIM + h];
      AD2[2 * k].y *= c.x;
      AD2[2 * k + 1].y *= c.y;
    }
#pragma unroll
    for (int k = 0; k < 14; ++k) {
      const f16x2 c = ft[FT3_OFF + k * H_DIM + h];
      AD1[2 * k].y *= c.x;
      if (2 * k + 1 < 27) AD1[2 * k + 1].y *= c.y;
    }
  } else {
    const float* f0h = f0 + h * 10;
    const float* f1h = f1 + h * 10;
#pragma unroll
    for (int l = 0; l < 10; ++l) AD3[l] *= mk2(f0h[l], f1h[l]);
    const float* f2h = f2 + h * 16;
#pragma unroll
    for (int l = 0; l < 16; ++l) AD2[l].y *= (f16)f2h[l];
    const float* f3h = f3 + h * 27;
#pragma unroll
    for (int l = 0; l < 27; ++l) AD1[l].y *= (f16)f3h[l];
  }

  f16x2 rr2[8];
  idwt_f16<16>([&](int s) -> f16 { return AD3[s].x; },
               [&](int s) -> f16 { return AD3[s].y; }, rr2);
  f16x2 rr1[14];
  idwt_f16<27>([&](int s) -> f16 { return (s & 1) ? rr2[s >> 1].y
                                                  : rr2[s >> 1].x; },
               [&](int s) -> f16 { return AD2[s].y; }, rr1);

  auto lo = [&](int s) -> f16 { return (s & 1) ? rr1[s >> 1].y
                                               : rr1[s >> 1].x; };
  auto hi = [&](int s) -> f16 { return AD1[s].y; };
#pragma unroll
  for (int t = 0; t < NPAIR; ++t) {
    f16x2 acc = mk2(0.f, 0.f);
#pragma unroll
    for (int k = 0; k < 3; ++k) {
      acc += splat2(lo(t + k)) * mk2(DLO[2 * k + 1], DLO[2 * k]);
      acc += splat2(hi(t + k)) * mk2(DHI[2 * k + 1], DHI[2 * k]);
    }
    yp[t] = xp[t] + acc;
  }
}

// Phase-0 staging: float4 global -> f16 pair-layout slab.
static __device__ __forceinline__ void stage_slab(const float4* __restrict__ in4,
                                                  f16* __restrict__ slab,
                                                  int tid) {
  f16x8* s8 = (f16x8*)slab;
#pragma unroll
  for (int i = 0; i < 7; ++i) {
    const int idx = i * 256 + tid;
    if (idx < NPAIR * 64) {
      const int t = idx >> 6, q = idx & 63;
      const float4 a = in4[(2 * t) * 64 + q];
      const float4 b = in4[(2 * t + 1) * 64 + q];
      f16x8 o;
      o.s0 = (f16)a.x; o.s1 = (f16)b.x;
      o.s2 = (f16)a.y; o.s3 = (f16)b.y;
      o.s4 = (f16)a.z; o.s5 = (f16)b.z;
      o.s6 = (f16)a.w; o.s7 = (f16)b.w;
      s8[idx] = o;
    }
  }
}

// ---- Kernel W: wavelet only; y pairs -> d_ws ----
template <bool USE_WS>
__global__ __launch_bounds__(256)
__attribute__((amdgpu_waves_per_eu(5, 8)))
void wavelet_w(const float* __restrict__ in, const float* __restrict__ f0,
               const float* __restrict__ f1, const float* __restrict__ f2,
               const float* __restrict__ f3, const f16x2* __restrict__ ft,
               f16x2* __restrict__ yws) {
  __shared__ f16 slab[S_LEN * H_DIM];  // 25600 B
  const int tid = threadIdx.x;
  const size_t base = (size_t)blockIdx.x * (S_LEN * H_DIM);
  stage_slab((const float4*)(in + base), slab, tid);
  __syncthreads();

  f16x2 xp[NPAIR], yp[NPAIR];
  wavelet_core<USE_WS>((const f16x2*)slab, tid, ft, f0, f1, f2, f3, xp, yp);

  f16x2* yb = yws + (size_t)blockIdx.x * (NPAIR * H_DIM) + tid;
#pragma unroll
  for (int t = 0; t < NPAIR; ++t) yb[t * H_DIM] = yp[t];  // coalesced dwords
}

// ---- Kernel L: streaming LN; one wave per row-pair; no LDS, no barriers ----
__global__ __launch_bounds__(256, 8)
void ln_l(const f16x2* __restrict__ yws, const float* __restrict__ gam,
          const float* __restrict__ bet, float* __restrict__ out) {
  const int tid = threadIdx.x;
  const int lane = tid & 63;
  const float4 g4 = ((const float4*)gam)[lane];  // h = 4*lane .. 4*lane+3
  const float4 b4 = ((const float4*)bet)[lane];
  const int gw = blockIdx.x * 4 + (tid >> 6);
  const int stride = gridDim.x * 4;

  for (int i = gw; i < BATCH * NPAIR; i += stride) {
    const int b = i / NPAIR;
    const int t = i - b * NPAIR;
    const f16x8 v =
        ((const f16x8*)(yws + (size_t)b * (NPAIR * H_DIM) + t * H_DIM))[lane];
    const int4 iv = __builtin_bit_cast(int4, v);
    const f16x2 a0 = __builtin_bit_cast(f16x2, iv.x);  // (y_even, y_odd) h+0
    const f16x2 a1 = __builtin_bit_cast(f16x2, iv.y);
    const f16x2 a2 = __builtin_bit_cast(f16x2, iv.z);
    const f16x2 a3 = __builtin_bit_cast(f16x2, iv.w);
    f16x2 s = (a0 + a1) + (a2 + a3);       // (sum_even, sum_odd), pk
    f16x2 q = a0 * a0;
    q += a1 * a1; q += a2 * a2; q += a3 * a3;
#pragma unroll
    for (int o = 1; o <= 32; o <<= 1) {    // 6 levels x 2 chains = 12 DS ops
      s += shfl_pk(s, o);
      q += shfl_pk(q, o);
    }
    const float mue = (float)s.x * (1.0f / H_DIM);
    const float muo = (float)s.y * (1.0f / H_DIM);
    const float rse =
        rsqrtf(fmaxf((float)q.x * (1.0f / H_DIM) - mue * mue, 0.0f) + 1e-12f);
    const float rso =
        rsqrtf(fmaxf((float)q.y * (1.0f / H_DIM) - muo * muo, 0.0f) + 1e-12f);
    float4 oe, oo;
    oe.x = ((float)a0.x - mue) * rse * g4.x + b4.x;
    oe.y = ((float)a1.x - mue) * rse * g4.y + b4.y;
    oe.z = ((float)a2.x - mue) * rse * g4.z + b4.z;
    oe.w = ((float)a3.x - mue) * rse * g4.w + b4.w;
    oo.x = ((float)a0.y - muo) * rso * g4.x + b4.x;
    oo.y = ((float)a1.y - muo) * rso * g4.y + b4.y;
    oo.z = ((float)a2.y - muo) * rso * g4.z + b4.z;
    oo.w = ((float)a3.y - muo) * rso * g4.w + b4.w;
    float4* row4 = (float4*)(out + (size_t)b * (S_LEN * H_DIM) + 2 * t * H_DIM);
    row4[lane] = oe;        // row 2t, dense 1KB per wave
    row4[lane + 64] = oo;   // row 2t+1
  }
}

// ---- Fallback: r8 fused kernel ----
template <bool USE_WS>
__global__ __launch_bounds__(256)
__attribute__((amdgpu_waves_per_eu(5, 8)))
void wavelet_ln_fused(
    const float* __restrict__ in, const float* __restrict__ f0,
    const float* __restrict__ f1, const float* __restrict__ f2,
    const float* __restrict__ f3, const f16x2* __restrict__ ft,
    const float* __restrict__ gam, const float* __restrict__ bet,
    float* __restrict__ out) {
  __shared__ f16 slab[S_LEN * H_DIM];
  const int tid = threadIdx.x;
  const size_t base = (size_t)blockIdx.x * (S_LEN * H_DIM);
  stage_slab((const float4*)(in + base), slab, tid);
  __syncthreads();

  f16x2 xp[NPAIR], yp[NPAIR];
  wavelet_core<USE_WS>((const f16x2*)slab, tid, ft, f0, f1, f2, f3, xp, yp);
  __syncthreads();  // done reading pair layout; rewrite row-major
#pragma unroll
  for (int t = 0; t < NPAIR; ++t) {
    slab[(2 * t) * H_DIM + tid] = yp[t].x;
    slab[(2 * t + 1) * H_DIM + tid] = yp[t].y;
  }
  __syncthreads();

  const int lane = tid & 63;
  const int wv = tid >> 6;
  const int half = lane >> 5;
  const int hq = lane & 31;
  const float4 ga = ((const float4*)gam)[hq];
  const float4 gb = ((const float4*)gam)[hq + 32];
  const float4 ba = ((const float4*)bet)[hq];
  const float4 bb = ((const float4*)bet)[hq + 32];
  float* __restrict__ outp = out + base;
  for (int p = wv; p < NPAIR; p += 4) {
    const int row = 2 * p + half;
    const f16x4 va = *(const f16x4*)&slab[row * H_DIM + hq * 4];
    const f16x4 vb = *(const f16x4*)&slab[row * H_DIM + 128 + hq * 4];
    const float y0 = (float)va.x, y1 = (float)va.y;
    const float y2 = (float)va.z, y3 = (float)va.w;
    const float y4 = (float)vb.x, y5 = (float)vb.y;
    const float y6 = (float)vb.z, y7 = (float)vb.w;
    float sum = ((y0 + y1) + (y2 + y3)) + ((y4 + y5) + (y6 + y7));
    float ssq = y0 * y0 + y1 * y1 + y2 * y2 + y3 * y3 +
                y4 * y4 + y5 * y5 + y6 * y6 + y7 * y7;
#pragma unroll
    for (int o = 16; o >= 1; o >>= 1) {
      sum += __shfl_xor(sum, o);
      ssq += __shfl_xor(ssq, o);
    }
    const float mu = sum * (1.0f / H_DIM);
    const float var = fmaxf(ssq * (1.0f / H_DIM) - mu * mu, 0.0f);
    const float rs = rsqrtf(var + 1e-12f);
    float4 o1, o2;
    o1.x = (y0 - mu) * rs * ga.x + ba.x;
    o1.y = (y1 - mu) * rs * ga.y + ba.y;
    o1.z = (y2 - mu) * rs * ga.z + ba.z;
    o1.w = (y3 - mu) * rs * ga.w + ba.w;
    o2.x = (y4 - mu) * rs * gb.x + bb.x;
    o2.y = (y5 - mu) * rs * gb.y + bb.y;
    o2.z = (y6 - mu) * rs * gb.z + bb.z;
    o2.w = (y7 - mu) * rs * gb.w + bb.w;
    float4* row4 = (float4*)(outp + row * H_DIM);
    row4[hq] = o1;
    row4[hq + 32] = o2;
  }
}

extern "C" void kernel_launch(void* const* d_in, const int* in_sizes, int n_in,
                              void* d_out, int out_size, void* d_ws,
                              size_t ws_size, hipStream_t stream) {
  // setup_inputs() dict order: input_tensor, ln_gamma, ln_beta, filt0..filt3
  const float* in = (const float*)d_in[0];
  const float* gam = (const float*)d_in[1];
  const float* bet = (const float*)d_in[2];
  const float* f0 = (const float*)d_in[3];
  const float* f1 = (const float*)d_in[4];
  const float* f2 = (const float*)d_in[5];
  const float* f3 = (const float*)d_in[6];
  float* out = (float*)d_out;

  if (ws_size >= (size_t)FT_BYTES + Y_BYTES) {
    f16x2* ft = (f16x2*)d_ws;
    f16x2* yws = (f16x2*)((char*)d_ws + FT_BYTES);
    prep_filters<<<32, 256, 0, stream>>>(f0, f1, f2, f3, ft);
    wavelet_w<true><<<BATCH, 256, 0, stream>>>(in, f0, f1, f2, f3, ft, yws);
    ln_l<<<2048, 256, 0, stream>>>(yws, gam, bet, out);
  } else if (ws_size >= (size_t)FT_BYTES) {
    f16x2* ft = (f16x2*)d_ws;
    prep_filters<<<32, 256, 0, stream>>>(f0, f1, f2, f3, ft);
    wavelet_ln_fused<true><<<BATCH, 256, 0, stream>>>(in, f0, f1, f2, f3, ft,
                                                      gam, bet, out);
  } else {
    wavelet_ln_fused<false><<<BATCH, 256, 0, stream>>>(
        in, f0, f1, f2, f3, nullptr, gam, bet, out);
  }
}

// Round 13
// 96.699 us; speedup vs baseline: 1.5244x; 1.5244x over previous
//
#include <hip/hip_runtime.h>
#include <math.h>

// WaveletLayer: (B=4096, S=50, H=256) fp32.
// Per (b,h): 3-level db3 wavedec (ptwt reflect) -> per-band filter multiply ->
// waverec -> +residual -> LayerNorm over H.
// Round-12 = r8 skeleton + packed micro-opts (r11's split refuted: y round-trip
// +210MB cancels any overlap gain; fused is structurally right):
//  (1) slab stays PAIR layout end-to-end; y written to own pair slots
//      (25 b32 writes, no relayout) -> 2 barriers total instead of 3.
//  (2) LN fully packed on pair layout: lane owns 4 h's (f16x8 = 4 even/odd
//      pairs), sum/ssq as 2 f16x2 chains, 12 pk shuffles per TWO rows,
//      f32 only for mu/rsqrt/normalize; dense 1KB float4 row stores.
//  (3) staging converts via v_cvt_pkrtz (half the cvt instructions).

#define S_LEN 50
#define H_DIM 256
#define NPAIR 25

typedef _Float16 f16;
typedef __attribute__((ext_vector_type(2))) _Float16 f16x2;
typedef __attribute__((ext_vector_type(8))) _Float16 f16x8;

// d_ws layout (f16x2 elements): ft01 [10][256] | ft2 [8][256] | ft3 [14][256]
#define FT01_OFF 0
#define FT2_OFF (10 * H_DIM)
#define FT3_OFF (18 * H_DIM)
#define FT_BYTES (32 * H_DIM * 4)  // 32768

__device__ constexpr float DLO[6] = {
    0.035226291882100656f, -0.08544127388224149f, -0.13501102001039084f,
    0.4598775021193313f,   0.8068915093133388f,   0.3326705529509569f};
__device__ constexpr float DHI[6] = {
    -0.3326705529509569f,  0.8068915093133388f,  -0.4598775021193313f,
    -0.13501102001039084f, 0.08544127388224149f,  0.035226291882100656f};

static __device__ __forceinline__ f16x2 splat2(f16 v) {
  f16x2 r; r.x = v; r.y = v; return r;
}
static __device__ __forceinline__ f16x2 mk2(float a, float b) {
  f16x2 r; r.x = (f16)a; r.y = (f16)b; return r;
}
static __device__ __forceinline__ f16x2 pk2(float a, float b) {
  return __builtin_bit_cast(f16x2, __builtin_amdgcn_cvt_pkrtz(a, b));
}
static __device__ __forceinline__ f16x2 shfl_pk(f16x2 v, int o) {
  return __builtin_bit_cast(f16x2, __shfl_xor(__builtin_bit_cast(int, v), o));
}

// Transpose+pack the learned filters into [l][h]-major f16x2 in ws.
__global__ void prep_filters(const float* __restrict__ f0,
                             const float* __restrict__ f1,
                             const float* __restrict__ f2,
                             const float* __restrict__ f3,
                             f16x2* __restrict__ ft) {
  const int h = threadIdx.x;
  const int b = blockIdx.x;
  if (b < 10) {  // (f0, f1) pair at tap l
    const int l = b;
    f16x2 v; v.x = (f16)f0[h * 10 + l]; v.y = (f16)f1[h * 10 + l];
    ft[FT01_OFF + l * H_DIM + h] = v;
  } else if (b < 18) {  // f2 taps (2k, 2k+1)
    const int k = b - 10;
    f16x2 v; v.x = (f16)f2[h * 16 + 2 * k]; v.y = (f16)f2[h * 16 + 2 * k + 1];
    ft[FT2_OFF + k * H_DIM + h] = v;
  } else {  // f3 taps (2k, 2k+1), last pair padded
    const int k = b - 18;
    f16x2 v;
    v.x = (f16)f3[h * 27 + 2 * k];
    v.y = (2 * k + 1 < 27) ? (f16)f3[h * 27 + 2 * k + 1] : (f16)0.f;
    ft[FT3_OFF + k * H_DIM + h] = v;
  }
}

// One analysis level, (lo,hi)-packed. out[i] = {cA[i], cD[i]}.
template <int N, class Get>
__device__ __forceinline__ void dwt_f16(const Get& X, f16x2* out) {
  constexpr int M = (N + 5) / 2;
#pragma unroll
  for (int i = 0; i < M; ++i) {
    f16x2 acc = mk2(0.f, 0.f);
#pragma unroll
    for (int j = 0; j < 6; ++j) {
      int idx = 2 * i + j - 4;
      idx = idx < 0 ? -idx : idx;
      idx = idx >= N ? 2 * N - 2 - idx : idx;
      acc += splat2(X(idx)) * mk2(DLO[5 - j], DHI[5 - j]);
    }
    out[i] = acc;
  }
}

// One synthesis level, adjacent-packed output: out2[t] = {rec[2t], rec[2t+1]}.
template <int T, class GLo, class GHi>
__device__ __forceinline__ void idwt_f16(const GLo& lo, const GHi& hi,
                                         f16x2* out2) {
#pragma unroll
  for (int t = 0; t < T / 2; ++t) {
    f16x2 acc = mk2(0.f, 0.f);
#pragma unroll
    for (int k = 0; k < 3; ++k) {
      acc += splat2(lo(t + k)) * mk2(DLO[2 * k + 1], DLO[2 * k]);
      acc += splat2(hi(t + k)) * mk2(DHI[2 * k + 1], DHI[2 * k]);
    }
    out2[t] = acc;
  }
  if constexpr (T & 1) {  // tail p = T-1 (even): taps {1,3,5}
    constexpr int t0 = T / 2;
    f16 s = (f16)0.f;
#pragma unroll
    for (int k = 0; k < 3; ++k)
      s += lo(t0 + k) * (f16)DLO[2 * k + 1] + hi(t0 + k) * (f16)DHI[2 * k + 1];
    f16x2 r; r.x = s; r.y = (f16)0.f;
    out2[t0] = r;
  }
}

template <bool USE_WS>
__global__ __launch_bounds__(256)
__attribute__((amdgpu_waves_per_eu(5, 8)))
void wavelet_ln_kernel(
    const float* __restrict__ in, const float* __restrict__ f0,
    const float* __restrict__ f1, const float* __restrict__ f2,
    const float* __restrict__ f3, const f16x2* __restrict__ ft,
    const float* __restrict__ gam, const float* __restrict__ bet,
    float* __restrict__ out) {
  __shared__ f16x2 slab[NPAIR * H_DIM];  // pair layout [t][h], 25600 B
  const int tid = threadIdx.x;
  const size_t base = (size_t)blockIdx.x * (S_LEN * H_DIM);
  const float4* in4 = (const float4*)(in + base);

  // ---- phase 0: stage x as f16 pairs {x[2t],x[2t+1]} per h (float4 loads,
  //      cvt_pkrtz packing: 4 pack instr per chunk) ----
  {
    int4* s4 = (int4*)slab;
#pragma unroll
    for (int i = 0; i < 7; ++i) {
      const int idx = i * 256 + tid;  // quad-of-pairs index in [0,1600)
      if (idx < NPAIR * 64) {
        const int t = idx >> 6, q = idx & 63;
        const float4 a = in4[(2 * t) * 64 + q];
        const float4 b = in4[(2 * t + 1) * 64 + q];
        int4 o;
        o.x = __builtin_bit_cast(int, pk2(a.x, b.x));
        o.y = __builtin_bit_cast(int, pk2(a.y, b.y));
        o.z = __builtin_bit_cast(int, pk2(a.z, b.z));
        o.w = __builtin_bit_cast(int, pk2(a.w, b.w));
        s4[idx] = o;
      }
    }
  }
  __syncthreads();

  const int h = tid;

  // ---- phase A: packed fp16 wavelet pipeline on own column; y written back
  //      to the SAME pair slots (own column only -> no barrier needed) ----
  {
    f16x2 xp[NPAIR];
#pragma unroll
    for (int t = 0; t < NPAIR; ++t) xp[t] = slab[t * H_DIM + h];  // 2-way free

    f16x2 AD1[27];
    dwt_f16<50>([&](int s) -> f16 { return (s & 1) ? xp[s >> 1].y
                                                   : xp[s >> 1].x; }, AD1);
    f16x2 AD2[16];
    dwt_f16<27>([&](int s) -> f16 { return AD1[s].x; }, AD2);
    f16x2 AD3[10];
    dwt_f16<16>([&](int s) -> f16 { return AD2[s].x; }, AD3);

    // per-band learned filter multiply
    if constexpr (USE_WS) {
#pragma unroll
      for (int l = 0; l < 10; ++l) AD3[l] *= ft[FT01_OFF + l * H_DIM + h];
#pragma unroll
      for (int k = 0; k < 8; ++k) {
        const f16x2 c = ft[FT2_OFF + k * H_DIM + h];
        AD2[2 * k].y *= c.x;
        AD2[2 * k + 1].y *= c.y;
      }
#pragma unroll
      for (int k = 0; k < 14; ++k) {
        const f16x2 c = ft[FT3_OFF + k * H_DIM + h];
        AD1[2 * k].y *= c.x;
        if (2 * k + 1 < 27) AD1[2 * k + 1].y *= c.y;
      }
    } else {  // fallback: direct (gathered) loads
      const float* f0h = f0 + h * 10;
      const float* f1h = f1 + h * 10;
#pragma unroll
      for (int l = 0; l < 10; ++l) AD3[l] *= mk2(f0h[l], f1h[l]);
      const float* f2h = f2 + h * 16;
#pragma unroll
      for (int l = 0; l < 16; ++l) AD2[l].y *= (f16)f2h[l];
      const float* f3h = f3 + h * 27;
#pragma unroll
      for (int l = 0; l < 27; ++l) AD1[l].y *= (f16)f3h[l];
    }

    // synthesis
    f16x2 rr2[8];
    idwt_f16<16>([&](int s) -> f16 { return AD3[s].x; },
                 [&](int s) -> f16 { return AD3[s].y; }, rr2);
    f16x2 rr1[14];
    idwt_f16<27>([&](int s) -> f16 { return (s & 1) ? rr2[s >> 1].y
                                                    : rr2[s >> 1].x; },
                 [&](int s) -> f16 { return AD2[s].y; }, rr1);

    auto lo = [&](int s) -> f16 { return (s & 1) ? rr1[s >> 1].y
                                                 : rr1[s >> 1].x; };
    auto hi = [&](int s) -> f16 { return AD1[s].y; };
#pragma unroll
    for (int t = 0; t < NPAIR; ++t) {
      f16x2 acc = mk2(0.f, 0.f);
#pragma unroll
      for (int k = 0; k < 3; ++k) {
        acc += splat2(lo(t + k)) * mk2(DLO[2 * k + 1], DLO[2 * k]);
        acc += splat2(hi(t + k)) * mk2(DHI[2 * k + 1], DHI[2 * k]);
      }
      slab[t * H_DIM + h] = xp[t] + acc;  // y pair -> own slot (1 b32 write)
    }
  }
  __syncthreads();

  // ---- phase B: packed LN on pair layout; wave handles row-pair t;
  //      lane owns h = 4*lane .. 4*lane+3 (f16x8 = 4 even/odd pairs) ----
  const int lane = tid & 63;
  const int wv = tid >> 6;
  const float4 g4 = ((const float4*)gam)[lane];
  const float4 b4 = ((const float4*)bet)[lane];
  float* __restrict__ outp = out + base;
  for (int t = wv; t < NPAIR; t += 4) {
    const f16x8 v = ((const f16x8*)(slab + t * H_DIM))[lane];  // b128, 2-way
    const int4 iv = __builtin_bit_cast(int4, v);
    const f16x2 p0 = __builtin_bit_cast(f16x2, iv.x);  // (y[2t], y[2t+1]) h+0
    const f16x2 p1 = __builtin_bit_cast(f16x2, iv.y);
    const f16x2 p2 = __builtin_bit_cast(f16x2, iv.z);
    const f16x2 p3 = __builtin_bit_cast(f16x2, iv.w);
    f16x2 s = (p0 + p1) + (p2 + p3);  // (sum_even_row, sum_odd_row)
    f16x2 q = p0 * p0;
    q += p1 * p1; q += p2 * p2; q += p3 * p3;
#pragma unroll
    for (int o = 1; o <= 32; o <<= 1) {  // 6 levels x 2 pk chains
      s += shfl_pk(s, o);
      q += shfl_pk(q, o);
    }
    const float mue = (float)s.x * (1.0f / H_DIM);
    const float muo = (float)s.y * (1.0f / H_DIM);
    const float rse =
        rsqrtf(fmaxf((float)q.x * (1.0f / H_DIM) - mue * mue, 0.0f) + 1e-12f);
    const float rso =
        rsqrtf(fmaxf((float)q.y * (1.0f / H_DIM) - muo * muo, 0.0f) + 1e-12f);
    float4 oe, oo;
    oe.x = ((float)p0.x - mue) * rse * g4.x + b4.x;
    oe.y = ((float)p1.x - mue) * rse * g4.y + b4.y;
    oe.z = ((float)p2.x - mue) * rse * g4.z + b4.z;
    oe.w = ((float)p3.x - mue) * rse * g4.w + b4.w;
    oo.x = ((float)p0.y - muo) * rso * g4.x + b4.x;
    oo.y = ((float)p1.y - muo) * rso * g4.y + b4.y;
    oo.z = ((float)p2.y - muo) * rso * g4.z + b4.z;
    oo.w = ((float)p3.y - muo) * rso * g4.w + b4.w;
    float4* r0 = (float4*)(outp + (2 * t) * H_DIM);
    float4* r1 = (float4*)(outp + (2 * t + 1) * H_DIM);
    r0[lane] = oe;  // dense 1KB per wave store
    r1[lane] = oo;
  }
}

extern "C" void kernel_launch(void* const* d_in, const int* in_sizes, int n_in,
                              void* d_out, int out_size, void* d_ws,
                              size_t ws_size, hipStream_t stream) {
  // setup_inputs() dict order: input_tensor, ln_gamma, ln_beta, filt0..filt3
  const float* in = (const float*)d_in[0];
  const float* gam = (const float*)d_in[1];
  const float* bet = (const float*)d_in[2];
  const float* f0 = (const float*)d_in[3];
  const float* f1 = (const float*)d_in[4];
  const float* f2 = (const float*)d_in[5];
  const float* f3 = (const float*)d_in[6];
  float* out = (float*)d_out;

  if (ws_size >= (size_t)FT_BYTES) {
    f16x2* ft = (f16x2*)d_ws;
    prep_filters<<<32, 256, 0, stream>>>(f0, f1, f2, f3, ft);
    wavelet_ln_kernel<true><<<4096, 256, 0, stream>>>(in, f0, f1, f2, f3, ft,
                                                      gam, bet, out);
  } else {
    wavelet_ln_kernel<false><<<4096, 256, 0, stream>>>(
        in, f0, f1, f2, f3, nullptr, gam, bet, out);
  }
}

// Round 14
// 94.548 us; speedup vs baseline: 1.5591x; 1.0228x over previous
//
#include <hip/hip_runtime.h>
#include <math.h>

// WaveletLayer: (B=4096, S=50, H=256) fp32.
// Per (b,h): 3-level db3 wavedec (ptwt reflect) -> per-band filter multiply ->
// waverec -> +residual -> LayerNorm over H.
// Round-13 = r12 + WAVE-LOCAL staging (barrier 1 of 2 removed):
//   wave w stages exactly the h-stripe [64w,64w+64) its own lanes consume ->
//   stage->compute dependency is wave-internal (lgkmcnt + wave_barrier, no
//   __syncthreads). The block's 4 waves desync through the long stage+compute
//   phase: one wave's VMEM overlaps another's VALU. One barrier remains
//   (before LN, irreducible: LN reads all 256 h).
// r12 carried: pair-layout slab end-to-end, packed LN (12 pk shuffles / 2
// rows), cvt_pkrtz staging, ft filter transpose in d_ws.

#define S_LEN 50
#define H_DIM 256
#define NPAIR 25

typedef _Float16 f16;
typedef __attribute__((ext_vector_type(2))) _Float16 f16x2;
typedef __attribute__((ext_vector_type(8))) _Float16 f16x8;

// d_ws layout (f16x2 elements): ft01 [10][256] | ft2 [8][256] | ft3 [14][256]
#define FT01_OFF 0
#define FT2_OFF (10 * H_DIM)
#define FT3_OFF (18 * H_DIM)
#define FT_BYTES (32 * H_DIM * 4)  // 32768

__device__ constexpr float DLO[6] = {
    0.035226291882100656f, -0.08544127388224149f, -0.13501102001039084f,
    0.4598775021193313f,   0.8068915093133388f,   0.3326705529509569f};
__device__ constexpr float DHI[6] = {
    -0.3326705529509569f,  0.8068915093133388f,  -0.4598775021193313f,
    -0.13501102001039084f, 0.08544127388224149f,  0.035226291882100656f};

static __device__ __forceinline__ f16x2 splat2(f16 v) {
  f16x2 r; r.x = v; r.y = v; return r;
}
static __device__ __forceinline__ f16x2 mk2(float a, float b) {
  f16x2 r; r.x = (f16)a; r.y = (f16)b; return r;
}
static __device__ __forceinline__ f16x2 pk2(float a, float b) {
  return __builtin_bit_cast(f16x2, __builtin_amdgcn_cvt_pkrtz(a, b));
}
static __device__ __forceinline__ f16x2 shfl_pk(f16x2 v, int o) {
  return __builtin_bit_cast(f16x2, __shfl_xor(__builtin_bit_cast(int, v), o));
}

// Transpose+pack the learned filters into [l][h]-major f16x2 in ws.
__global__ void prep_filters(const float* __restrict__ f0,
                             const float* __restrict__ f1,
                             const float* __restrict__ f2,
                             const float* __restrict__ f3,
                             f16x2* __restrict__ ft) {
  const int h = threadIdx.x;
  const int b = blockIdx.x;
  if (b < 10) {  // (f0, f1) pair at tap l
    const int l = b;
    f16x2 v; v.x = (f16)f0[h * 10 + l]; v.y = (f16)f1[h * 10 + l];
    ft[FT01_OFF + l * H_DIM + h] = v;
  } else if (b < 18) {  // f2 taps (2k, 2k+1)
    const int k = b - 10;
    f16x2 v; v.x = (f16)f2[h * 16 + 2 * k]; v.y = (f16)f2[h * 16 + 2 * k + 1];
    ft[FT2_OFF + k * H_DIM + h] = v;
  } else {  // f3 taps (2k, 2k+1), last pair padded
    const int k = b - 18;
    f16x2 v;
    v.x = (f16)f3[h * 27 + 2 * k];
    v.y = (2 * k + 1 < 27) ? (f16)f3[h * 27 + 2 * k + 1] : (f16)0.f;
    ft[FT3_OFF + k * H_DIM + h] = v;
  }
}

// One analysis level, (lo,hi)-packed. out[i] = {cA[i], cD[i]}.
template <int N, class Get>
__device__ __forceinline__ void dwt_f16(const Get& X, f16x2* out) {
  constexpr int M = (N + 5) / 2;
#pragma unroll
  for (int i = 0; i < M; ++i) {
    f16x2 acc = mk2(0.f, 0.f);
#pragma unroll
    for (int j = 0; j < 6; ++j) {
      int idx = 2 * i + j - 4;
      idx = idx < 0 ? -idx : idx;
      idx = idx >= N ? 2 * N - 2 - idx : idx;
      acc += splat2(X(idx)) * mk2(DLO[5 - j], DHI[5 - j]);
    }
    out[i] = acc;
  }
}

// One synthesis level, adjacent-packed output: out2[t] = {rec[2t], rec[2t+1]}.
template <int T, class GLo, class GHi>
__device__ __forceinline__ void idwt_f16(const GLo& lo, const GHi& hi,
                                         f16x2* out2) {
#pragma unroll
  for (int t = 0; t < T / 2; ++t) {
    f16x2 acc = mk2(0.f, 0.f);
#pragma unroll
    for (int k = 0; k < 3; ++k) {
      acc += splat2(lo(t + k)) * mk2(DLO[2 * k + 1], DLO[2 * k]);
      acc += splat2(hi(t + k)) * mk2(DHI[2 * k + 1], DHI[2 * k]);
    }
    out2[t] = acc;
  }
  if constexpr (T & 1) {  // tail p = T-1 (even): taps {1,3,5}
    constexpr int t0 = T / 2;
    f16 s = (f16)0.f;
#pragma unroll
    for (int k = 0; k < 3; ++k)
      s += lo(t0 + k) * (f16)DLO[2 * k + 1] + hi(t0 + k) * (f16)DHI[2 * k + 1];
    f16x2 r; r.x = s; r.y = (f16)0.f;
    out2[t0] = r;
  }
}

template <bool USE_WS>
__global__ __launch_bounds__(256)
__attribute__((amdgpu_waves_per_eu(5, 8)))
void wavelet_ln_kernel(
    const float* __restrict__ in, const float* __restrict__ f0,
    const float* __restrict__ f1, const float* __restrict__ f2,
    const float* __restrict__ f3, const f16x2* __restrict__ ft,
    const float* __restrict__ gam, const float* __restrict__ bet,
    float* __restrict__ out) {
  __shared__ f16x2 slab[NPAIR * H_DIM];  // pair layout [t][h], 25600 B
  const int tid = threadIdx.x;
  const size_t base = (size_t)blockIdx.x * (S_LEN * H_DIM);
  const float4* in4 = (const float4*)(in + base);

  // ---- phase 0: WAVE-LOCAL staging. Wave w loads & packs the h-stripe
  //      [64w, 64w+64) that its own lanes consume. 256B segments/instr. ----
  {
    const int w = tid >> 6, l = tid & 63;
    int4* s4 = (int4*)slab;  // one int4 = 4 consecutive h-pairs
#pragma unroll
    for (int i = 0; i < 7; ++i) {
      const int flat = i * 64 + l;  // stripe-local index in [0, 400)
      if (flat < NPAIR * 16) {
        const int t = flat >> 4;        // row-pair
        const int gq = 16 * w + (flat & 15);  // h-quad in [0,64)
        const float4 a = in4[(2 * t) * 64 + gq];
        const float4 b = in4[(2 * t + 1) * 64 + gq];
        int4 o;
        o.x = __builtin_bit_cast(int, pk2(a.x, b.x));
        o.y = __builtin_bit_cast(int, pk2(a.y, b.y));
        o.z = __builtin_bit_cast(int, pk2(a.z, b.z));
        o.w = __builtin_bit_cast(int, pk2(a.w, b.w));
        s4[t * 64 + gq] = o;  // pair idx (t*256+4*gq)/4
      }
    }
  }
  // stage->compute dependency is wave-internal: no __syncthreads needed.
  __builtin_amdgcn_wave_barrier();  // scheduling fence; HW lgkmcnt orders LDS

  const int h = tid;

  // ---- phase A: packed fp16 wavelet pipeline on own column; y written back
  //      to the SAME pair slots (own column only -> no barrier needed) ----
  {
    f16x2 xp[NPAIR];
#pragma unroll
    for (int t = 0; t < NPAIR; ++t) xp[t] = slab[t * H_DIM + h];  // 2-way free

    f16x2 AD1[27];
    dwt_f16<50>([&](int s) -> f16 { return (s & 1) ? xp[s >> 1].y
                                                   : xp[s >> 1].x; }, AD1);
    f16x2 AD2[16];
    dwt_f16<27>([&](int s) -> f16 { return AD1[s].x; }, AD2);
    f16x2 AD3[10];
    dwt_f16<16>([&](int s) -> f16 { return AD2[s].x; }, AD3);

    // per-band learned filter multiply
    if constexpr (USE_WS) {
#pragma unroll
      for (int l = 0; l < 10; ++l) AD3[l] *= ft[FT01_OFF + l * H_DIM + h];
#pragma unroll
      for (int k = 0; k < 8; ++k) {
        const f16x2 c = ft[FT2_OFF + k * H_DIM + h];
        AD2[2 * k].y *= c.x;
        AD2[2 * k + 1].y *= c.y;
      }
#pragma unroll
      for (int k = 0; k < 14; ++k) {
        const f16x2 c = ft[FT3_OFF + k * H_DIM + h];
        AD1[2 * k].y *= c.x;
        if (2 * k + 1 < 27) AD1[2 * k + 1].y *= c.y;
      }
    } else {  // fallback: direct (gathered) loads
      const float* f0h = f0 + h * 10;
      const float* f1h = f1 + h * 10;
#pragma unroll
      for (int l = 0; l < 10; ++l) AD3[l] *= mk2(f0h[l], f1h[l]);
      const float* f2h = f2 + h * 16;
#pragma unroll
      for (int l = 0; l < 16; ++l) AD2[l].y *= (f16)f2h[l];
      const float* f3h = f3 + h * 27;
#pragma unroll
      for (int l = 0; l < 27; ++l) AD1[l].y *= (f16)f3h[l];
    }

    // synthesis
    f16x2 rr2[8];
    idwt_f16<16>([&](int s) -> f16 { return AD3[s].x; },
                 [&](int s) -> f16 { return AD3[s].y; }, rr2);
    f16x2 rr1[14];
    idwt_f16<27>([&](int s) -> f16 { return (s & 1) ? rr2[s >> 1].y
                                                    : rr2[s >> 1].x; },
                 [&](int s) -> f16 { return AD2[s].y; }, rr1);

    auto lo = [&](int s) -> f16 { return (s & 1) ? rr1[s >> 1].y
                                                 : rr1[s >> 1].x; };
    auto hi = [&](int s) -> f16 { return AD1[s].y; };
#pragma unroll
    for (int t = 0; t < NPAIR; ++t) {
      f16x2 acc = mk2(0.f, 0.f);
#pragma unroll
      for (int k = 0; k < 3; ++k) {
        acc += splat2(lo(t + k)) * mk2(DLO[2 * k + 1], DLO[2 * k]);
        acc += splat2(hi(t + k)) * mk2(DHI[2 * k + 1], DHI[2 * k]);
      }
      slab[t * H_DIM + h] = xp[t] + acc;  // y pair -> own slot (1 b32 write)
    }
  }
  __syncthreads();  // the one irreducible barrier: LN reads all 256 h

  // ---- phase B: packed LN on pair layout; wave handles row-pair t;
  //      lane owns h = 4*lane .. 4*lane+3 (f16x8 = 4 even/odd pairs) ----
  const int lane = tid & 63;
  const int wv = tid >> 6;
  const float4 g4 = ((const float4*)gam)[lane];
  const float4 b4 = ((const float4*)bet)[lane];
  float* __restrict__ outp = out + base;
  for (int t = wv; t < NPAIR; t += 4) {
    const f16x8 v = ((const f16x8*)(slab + t * H_DIM))[lane];  // b128, 2-way
    const int4 iv = __builtin_bit_cast(int4, v);
    const f16x2 p0 = __builtin_bit_cast(f16x2, iv.x);  // (y[2t], y[2t+1]) h+0
    const f16x2 p1 = __builtin_bit_cast(f16x2, iv.y);
    const f16x2 p2 = __builtin_bit_cast(f16x2, iv.z);
    const f16x2 p3 = __builtin_bit_cast(f16x2, iv.w);
    f16x2 s = (p0 + p1) + (p2 + p3);  // (sum_even_row, sum_odd_row)
    f16x2 q = p0 * p0;
    q += p1 * p1; q += p2 * p2; q += p3 * p3;
#pragma unroll
    for (int o = 1; o <= 32; o <<= 1) {  // 6 levels x 2 pk chains
      s += shfl_pk(s, o);
      q += shfl_pk(q, o);
    }
    const float mue = (float)s.x * (1.0f / H_DIM);
    const float muo = (float)s.y * (1.0f / H_DIM);
    const float rse =
        rsqrtf(fmaxf((float)q.x * (1.0f / H_DIM) - mue * mue, 0.0f) + 1e-12f);
    const float rso =
        rsqrtf(fmaxf((float)q.y * (1.0f / H_DIM) - muo * muo, 0.0f) + 1e-12f);
    float4 oe, oo;
    oe.x = ((float)p0.x - mue) * rse * g4.x + b4.x;
    oe.y = ((float)p1.x - mue) * rse * g4.y + b4.y;
    oe.z = ((float)p2.x - mue) * rse * g4.z + b4.z;
    oe.w = ((float)p3.x - mue) * rse * g4.w + b4.w;
    oo.x = ((float)p0.y - muo) * rso * g4.x + b4.x;
    oo.y = ((float)p1.y - muo) * rso * g4.y + b4.y;
    oo.z = ((float)p2.y - muo) * rso * g4.z + b4.z;
    oo.w = ((float)p3.y - muo) * rso * g4.w + b4.w;
    float4* r0 = (float4*)(outp + (2 * t) * H_DIM);
    float4* r1 = (float4*)(outp + (2 * t + 1) * H_DIM);
    r0[lane] = oe;  // dense 1KB per wave store
    r1[lane] = oo;
  }
}

extern "C" void kernel_launch(void* const* d_in, const int* in_sizes, int n_in,
                              void* d_out, int out_size, void* d_ws,
                              size_t ws_size, hipStream_t stream) {
  // setup_inputs() dict order: input_tensor, ln_gamma, ln_beta, filt0..filt3
  const float* in = (const float*)d_in[0];
  const float* gam = (const float*)d_in[1];
  const float* bet = (const float*)d_in[2];
  const float* f0 = (const float*)d_in[3];
  const float* f1 = (const float*)d_in[4];
  const float* f2 = (const float*)d_in[5];
  const float* f3 = (const float*)d_in[6];
  float* out = (float*)d_out;

  if (ws_size >= (size_t)FT_BYTES) {
    f16x2* ft = (f16x2*)d_ws;
    prep_filters<<<32, 256, 0, stream>>>(f0, f1, f2, f3, ft);
    wavelet_ln_kernel<true><<<4096, 256, 0, stream>>>(in, f0, f1, f2, f3, ft,
                                                      gam, bet, out);
  } else {
    wavelet_ln_kernel<false><<<4096, 256, 0, stream>>>(
        in, f0, f1, f2, f3, nullptr, gam, bet, out);
  }
}